// Round 22
// baseline (288.746 us; speedup 1.0000x reference)
//
#include <hip/hip_runtime.h>
#include <math.h>

// Problem geometry (fixed by the reference):
//   preds   : (2, 2, 128, 128, 128) float32
//   targets : (2, 1, 128, 128, 128) int32
//   output  : scalar = mean of 0.5*ce*(1 + 0.5*m_neg + 0.5*m_pos)
#define VOL   (128 * 128 * 128)
#define NB    2
#define TOTAL (NB * VOL)          // 4,194,304

#define INVP   0x7FFFFFFFu        // background sentinel in global parent arrays
#define FLAGB  0x80000000u        // "component has an error voxel" bit
#define TAGB   0x40000000u        // list-entry tag: 0 = pred array, 1 = tgt
#define GIDM   0x3FFFFFFFu        // list-entry gid mask (gid < 4M fits)
#define IDXM   0x7FFFFFFFu
#define LINV   0xFFFFFFFFu        // background sentinel in LDS label array

// 16x16x16 tiles: 8x8x8 per volume.
#define TPV            (8 * 8 * 8)             // 512
#define FACES_PER_DIR  (7 * 8 * 8)             // 448
#define FACES_PER_VOL  (3 * FACES_PER_DIR)     // 1344
#define NFACES         (NB * FACES_PER_VOL)    // 2688

// ---------------- global union-find (atomicMin-monotone, deterministic) ----
__device__ __forceinline__ unsigned find_root(unsigned* P, unsigned i) {
    while (true) {
        unsigned p = P[i] & IDXM;
        if (p == i) return i;
        unsigned gp = P[p] & IDXM;
        if (gp != p) atomicMin(&P[i], gp);   // halving never writes ROOT entries
        i = gp;
    }
}

__device__ __forceinline__ void unite(unsigned* P, unsigned a, unsigned b) {
    a = find_root(P, a);
    b = find_root(P, b);
    while (a != b) {
        if (b > a) { unsigned t = a; a = b; b = t; }
        unsigned old = atomicMin(&P[a], b);
        if (old == a) return;
        a = find_root(P, old & IDXM);
        b = find_root(P, b);
    }
}

// ---------------- LDS union-find ----------------
__device__ __forceinline__ unsigned lfind(unsigned* L, unsigned i) {
    while (true) {
        unsigned p = L[i];
        if (p == i) return i;
        unsigned gp = L[p];
        if (gp != p) atomicMin(&L[i], gp);
        i = gp;
    }
}

__device__ __forceinline__ void lunite(unsigned* L, unsigned a, unsigned b) {
    a = lfind(L, a);
    b = lfind(L, b);
    while (a != b) {
        if (b > a) { unsigned t = a; a = b; b = t; }
        unsigned old = atomicMin(&L[a], b);
        if (old == a) return;
        a = lfind(L, old);
        b = lfind(L, b);
    }
}

// ---------------- kernels ----------------

__global__ void k_zero(unsigned* __restrict__ cnts) {
    if (threadIdx.x < 4) cnts[threadIdx.x] = 0;
}

// Phase 1: init + tile-local CCL + per-root ERROR bit + combined root list.
// One block = one 16^3 tile. The two segmentations are processed
// SEQUENTIALLY through ONE 16 KB label array (fg masks kept as 512B bitsets,
// needed anyway for the cross-array error test). LDS 35.3 -> ~17.9 KB doubles
// blocks/CU 4 -> 8 (R21: latency-bound chases at 44% occupancy were the cost).
__global__ void k_local(const float* __restrict__ preds,
                        const int* __restrict__ tgt,
                        unsigned* __restrict__ Pp,
                        unsigned* __restrict__ Pt,
                        unsigned* __restrict__ list,
                        unsigned* __restrict__ cnts,
                        unsigned cap) {
    __shared__ unsigned lab[4096];               // 16 KB, reused per array
    __shared__ unsigned fgP[128], fgT[128], errb[128];   // bitsets
    __shared__ unsigned s_wtot[4];
    __shared__ unsigned s_gbase;
    unsigned tile = blockIdx.x;                  // 0..1023
    unsigned b  = tile >> 9;
    unsigned tz = (tile >> 6) & 7, ty = (tile >> 3) & 7, tx = tile & 7;
    unsigned base_v = tz * (16 * 16384) + ty * (16 * 128) + tx * 16;
    unsigned base_g = b * VOL + base_v;
    unsigned lane = threadIdx.x & 63, wid = threadIdx.x >> 6;

    if (threadIdx.x < 128) { fgP[threadIdx.x] = 0; fgT[threadIdx.x] = 0; }
    __syncthreads();
    // vectorized mask load -> fg bitsets (4 consecutive x-voxels per iter;
    // the 4 bits land in one aligned nibble of one word -> 1 atomicOr each)
    for (int base = threadIdx.x * 4; base < 4096; base += 1024) {
        unsigned lx = base & 15, ly = (base >> 4) & 15, lz = base >> 8;
        unsigned voli = base_v + lz * 16384 + ly * 128 + lx;
        float4 p1 = *reinterpret_cast<const float4*>(
            preds + (size_t)(b * 2 + 1) * VOL + voli);
        int4  t4 = *reinterpret_cast<const int4*>(tgt + b * VOL + voli);
        unsigned pm = ((p1.x > 0.0f) ? 1u : 0u) | ((p1.y > 0.0f) ? 2u : 0u) |
                      ((p1.z > 0.0f) ? 4u : 0u) | ((p1.w > 0.0f) ? 8u : 0u);
        unsigned tm = ((t4.x > 0) ? 1u : 0u) | ((t4.y > 0) ? 2u : 0u) |
                      ((t4.z > 0) ? 4u : 0u) | ((t4.w > 0) ? 8u : 0u);
        if (pm) atomicOr(&fgP[base >> 5], pm << (base & 31));
        if (tm) atomicOr(&fgT[base >> 5], tm << (base & 31));
    }
    __syncthreads();

    for (int arr = 0; arr < 2; ++arr) {
        unsigned* FG = arr ? fgT : fgP;          // this array's fg
        unsigned* OG = arr ? fgP : fgT;          // other array's fg (err test)
        unsigned* P  = arr ? Pt : Pp;
        unsigned tag = arr ? TAGB : 0u;

        // init labels from bitset (uint4 LDS write)
        for (int base = threadIdx.x * 4; base < 4096; base += 1024) {
            unsigned w = FG[base >> 5] >> (base & 31);
            uint4 v;
            v.x = (w & 1u) ? (unsigned)(base + 0) : LINV;
            v.y = (w & 2u) ? (unsigned)(base + 1) : LINV;
            v.z = (w & 4u) ? (unsigned)(base + 2) : LINV;
            v.w = (w & 8u) ? (unsigned)(base + 3) : LINV;
            *reinterpret_cast<uint4*>(&lab[base]) = v;
        }
        if (threadIdx.x < 128) errb[threadIdx.x] = 0;
        __syncthreads();

        // local unites over the 3 forward links
        for (int l = threadIdx.x; l < 4096; l += 256) {
            if (lab[l] != LINV) {
                unsigned lx = l & 15, ly = (l >> 4) & 15, lz = l >> 8;
                if (lx < 15 && lab[l + 1]   != LINV) lunite(lab, l, l + 1);
                if (ly < 15 && lab[l + 16]  != LINV) lunite(lab, l, l + 16);
                if (lz < 15 && lab[l + 256] != LINV) lunite(lab, l, l + 256);
            }
        }
        __syncthreads();

        // compress to tile root, write global parents, OR error bit onto root
        for (int l = threadIdx.x; l < 4096; l += 256) {
            unsigned lx = l & 15, ly = (l >> 4) & 15, lz = l >> 8;
            unsigned g = base_g + lz * 16384 + ly * 128 + lx;
            if (lab[l] != LINV) {
                unsigned r = lfind(lab, l);
                P[g] = base_g + (r >> 8) * 16384 + ((r >> 4) & 15) * 128 + (r & 15);
                if (!((OG[l >> 5] >> (l & 31)) & 1u))
                    atomicOr(&errb[r >> 5], 1u << (r & 31));
            } else P[g] = INVP;
        }
        __syncthreads();

        // collect roots: count, wave shfl-scan, cross-wave scan, emit
        unsigned myCnt = 0;
        for (int k = 0; k < 16; ++k) {
            int l = threadIdx.x + k * 256;
            myCnt += (lab[l] == (unsigned)l) ? 1u : 0u;
        }
        unsigned inc = myCnt;
        for (int off = 1; off < 64; off <<= 1) {
            unsigned n = __shfl_up(inc, off);
            if (lane >= (unsigned)off) inc += n;
        }
        if (lane == 63) s_wtot[wid] = inc;
        __syncthreads();
        if (threadIdx.x == 0) {
            unsigned tot = 0;
            for (int w = 0; w < 4; ++w) { unsigned t = s_wtot[w]; s_wtot[w] = tot; tot += t; }
            s_gbase = atomicAdd(&cnts[0], tot);
        }
        __syncthreads();
        unsigned idx = s_gbase + s_wtot[wid] + inc - myCnt;
        for (int k = 0; k < 16; ++k) {
            int l = threadIdx.x + k * 256;
            if (lab[l] == (unsigned)l) {
                if (idx < cap) {
                    unsigned gid = base_g + (l >> 8) * 16384 + ((l >> 4) & 15) * 128 + (l & 15);
                    unsigned eb = (errb[l >> 5] >> (l & 31)) & 1u;
                    list[idx] = gid | tag | (eb ? FLAGB : 0u);
                }
                idx++;
            }
        }
        __syncthreads();   // before reusing lab/errb for the next array
    }
}

// Phase 2: face-centric boundary merge (R12 form — measured cheap).
__global__ void k_bmerge(unsigned* __restrict__ Pp, unsigned* __restrict__ Pt) {
    unsigned fid = blockIdx.x;
    unsigned vol = fid / FACES_PER_VOL;
    unsigned r   = fid % FACES_PER_VOL;
    unsigned dir = r / FACES_PER_DIR;
    unsigned fr  = r % FACES_PER_DIR;
    unsigned b0 = fr % 7;
    unsigned t1 = (fr / 7) % 8;
    unsigned t2 = fr / 56;
    unsigned u = threadIdx.x & 15, v = threadIdx.x >> 4;
    unsigned lane = threadIdx.x & 63;

    unsigned x, y, z, step;
    if (dir == 0)      { x = b0 * 16 + 15; y = t1 * 16 + u; z = t2 * 16 + v; step = 1; }
    else if (dir == 1) { y = b0 * 16 + 15; x = t1 * 16 + u; z = t2 * 16 + v; step = 128; }
    else               { z = b0 * 16 + 15; x = t1 * 16 + u; y = t2 * 16 + v; step = 16384; }
    unsigned g = vol * VOL + z * 16384 + y * 128 + x;

    for (int arr = 0; arr < 2; ++arr) {
        unsigned* P = arr ? Pt : Pp;
        unsigned a = P[g];
        unsigned bb = P[g + step];
        bool need = (a != INVP) && (bb != INVP);
        bool leader = false;
        unsigned long long rem = __ballot(need);
        while (rem) {
            int src = __ffsll(rem) - 1;
            unsigned sa = __shfl(a, src), sb = __shfl(bb, src);
            if (need && a == sa && bb == sb) {
                leader = ((int)lane == src);
                need = false;
            }
            rem = __ballot(need);
        }
        if (leader) unite(P, a, bb);
    }
}

// Phase 2b: per listed tile root — link directly to global root AND flag the
// global root if the local component carried an error (entry MSB). O(#roots).
__global__ void k_rcompress(unsigned* __restrict__ Pp, unsigned* __restrict__ Pt,
                            const unsigned* __restrict__ list,
                            const unsigned* __restrict__ cnts, unsigned cap) {
    unsigned n = cnts[0] < cap ? cnts[0] : cap;
    for (unsigned i = blockIdx.x * blockDim.x + threadIdx.x; i < n;
         i += gridDim.x * blockDim.x) {
        unsigned e = list[i];
        unsigned* P = (e & TAGB) ? Pt : Pp;
        unsigned r = e & GIDM;
        unsigned rt = find_root(P, r);
        if (rt != r) atomicMin(&P[r], rt);         // direct link
        if ((e & FLAGB) && !(P[rt] & FLAGB)) atomicOr(&P[rt], FLAGB);
    }
}

// Phase 3: pull flags down onto tile-root entries (exactly what k_loss reads).
__global__ void k_rpull(unsigned* __restrict__ Pp, unsigned* __restrict__ Pt,
                        const unsigned* __restrict__ list,
                        const unsigned* __restrict__ cnts, unsigned cap) {
    unsigned n = cnts[0] < cap ? cnts[0] : cap;
    for (unsigned i = blockIdx.x * blockDim.x + threadIdx.x; i < n;
         i += gridDim.x * blockDim.x) {
        unsigned e = list[i];
        unsigned* P = (e & TAGB) ? Pt : Pp;
        unsigned r = e & GIDM;
        unsigned root = P[r] & IDXM;               // direct after rcompress
        if ((P[root] & FLAGB) && !(P[r] & FLAGB)) atomicOr(&P[r], FLAGB);
    }
}

__global__ void k_loss(const float* __restrict__ preds,
                       const int* __restrict__ tgt,
                       const unsigned* __restrict__ Pp,
                       const unsigned* __restrict__ Pt,
                       float* __restrict__ partial) {
    float acc = 0.0f;
    for (unsigned g4 = (blockIdx.x * blockDim.x + threadIdx.x) * 4; g4 < TOTAL;
         g4 += gridDim.x * blockDim.x * 4) {
        unsigned b = g4 >> 21;
        unsigned i = g4 & (VOL - 1);
        float4 p0 = *reinterpret_cast<const float4*>(preds + (size_t)(b * 2 + 0) * VOL + i);
        float4 p1 = *reinterpret_cast<const float4*>(preds + (size_t)(b * 2 + 1) * VOL + i);
        int4  t4  = *reinterpret_cast<const int4*>(tgt + g4);
        uint4 vp4 = *reinterpret_cast<const uint4*>(Pp + g4);
        uint4 vt4 = *reinterpret_cast<const uint4*>(Pt + g4);
        float p0a[4] = {p0.x, p0.y, p0.z, p0.w};
        float p1a[4] = {p1.x, p1.y, p1.z, p1.w};
        int   ta[4]  = {t4.x, t4.y, t4.z, t4.w};
        unsigned vpa[4] = {vp4.x, vp4.y, vp4.z, vp4.w};
        unsigned vta[4] = {vt4.x, vt4.y, vt4.z, vt4.w};
        #pragma unroll
        for (int j = 0; j < 4; ++j) {
            float z  = (ta[j] > 0) ? (p0a[j] - p1a[j]) : (p1a[j] - p0a[j]);
            float ce = (z > 0.0f) ? (z + log1pf(expf(-z))) : log1pf(expf(z));
            float crit = 0.0f;
            if (vta[j] != INVP) {
                unsigned r = vta[j] & IDXM;
                if (Pt[r] & FLAGB) crit += 0.5f;     // BETA * m_neg
            }
            if (vpa[j] != INVP) {
                unsigned r = vpa[j] & IDXM;
                if (Pp[r] & FLAGB) crit += 0.5f;     // (1-BETA) * m_pos
            }
            acc += 0.5f * ce * (1.0f + crit);
        }
    }
    for (int off = 32; off > 0; off >>= 1) acc += __shfl_down(acc, off);
    __shared__ float s[4];
    int wid = threadIdx.x >> 6, lane = threadIdx.x & 63;
    if (lane == 0) s[wid] = acc;
    __syncthreads();
    if (threadIdx.x == 0) {
        float tacc = 0.0f;
        for (int w = 0; w < (int)(blockDim.x >> 6); ++w) tacc += s[w];
        partial[blockIdx.x] = tacc;
    }
}

__global__ void k_final(const float* __restrict__ partial, int n,
                        float* __restrict__ out) {
    double acc = 0.0;
    for (int i = threadIdx.x; i < n; i += blockDim.x) acc += (double)partial[i];
    for (int off = 32; off > 0; off >>= 1) acc += __shfl_down(acc, off);
    __shared__ double s[4];
    int wid = threadIdx.x >> 6, lane = threadIdx.x & 63;
    if (lane == 0) s[wid] = acc;
    __syncthreads();
    if (threadIdx.x == 0) {
        double t = 0.0;
        for (int w = 0; w < (int)(blockDim.x >> 6); ++w) t += s[w];
        out[0] = (float)(t / (double)TOTAL);
    }
}

// ---------------- launch ----------------

extern "C" void kernel_launch(void* const* d_in, const int* in_sizes, int n_in,
                              void* d_out, int out_size, void* d_ws, size_t ws_size,
                              hipStream_t stream) {
    const float* preds   = (const float*)d_in[0];
    const int*   targets = (const int*)d_in[1];
    float*       out     = (float*)d_out;

    // ws layout: Pp[4M] | Pt[4M] | partial[2048] f32 | cnts[4] | list
    unsigned* Pp = (unsigned*)d_ws;
    unsigned* Pt = Pp + TOTAL;
    float* partial = (float*)(Pt + TOTAL);
    unsigned* cnts = (unsigned*)(partial + 2048);
    unsigned* list = cnts + 4;
    size_t used = (size_t)((char*)list - (char*)d_ws);
    size_t avail = ws_size > used ? ws_size - used : 0;
    size_t cap_sz = avail / 4;
    unsigned cap = cap_sz > 1048576 ? 1048576u : (unsigned)cap_sz;

    const int T = 256;
    const int NTILE = NB * TPV;               // 1024 tiles
    k_zero     <<<1, 64, 0, stream>>>(cnts);
    k_local    <<<NTILE, T, 0, stream>>>(preds, targets, Pp, Pt, list, cnts, cap);
    k_bmerge   <<<NFACES, T, 0, stream>>>(Pp, Pt);
    k_rcompress<<<128, T, 0, stream>>>(Pp, Pt, list, cnts, cap);
    k_rpull    <<<128, T, 0, stream>>>(Pp, Pt, list, cnts, cap);

    const int RB = 2048;
    k_loss <<<RB, T, 0, stream>>>(preds, targets, Pp, Pt, partial);
    k_final<<<1, T, 0, stream>>>(partial, RB, out);
}